// Round 3
// baseline (2135.238 us; speedup 1.0000x reference)
//
#include <hip/hip_runtime.h>
#include <stdint.h>

typedef unsigned int u32;
typedef unsigned short u16;
typedef __attribute__((ext_vector_type(8))) __bf16 bf16x8;
typedef __attribute__((ext_vector_type(4))) float f32x4;
typedef __attribute__((ext_vector_type(4))) u32 u32x4;

#define NSTEPS 256
// ---- workspace layout ----
#define XB_BYTES   67108864u              // x as bf16: 512*256*256*2
#define SL_OFF     XB_BYTES               // h slots: [slot][group][row 0..63][col 0..511] bf16
#define GRP_BYTES   65536u                // 64 rows * 1024B
#define SLOT_BYTES  524288u               // 8 groups
#define CNT_OFF    (SL_OFF + 2u * SLOT_BYTES)   // [group][wave] counters, 128B apart
// ---- LDS layout ----
#define W_ROWB 1536                       // 768 bf16 per weight row (row = gate*16 + localcol)
#define H_OFF  98304                      // 64 rows * 1536
#define LDS_TOTAL 163840                  // + 64 rows * 1024 (h tile) = 160 KiB exactly

static __device__ __forceinline__ u16 f2bf(float f) {
  u32 u = __builtin_bit_cast(u32, f);
  return (u16)((u + 0x7fffu + ((u >> 16) & 1u)) >> 16);   // RNE
}
static __device__ __forceinline__ float bf2f(u16 h) {
  u32 u = ((u32)h) << 16;
  return __builtin_bit_cast(float, u);
}
static __device__ __forceinline__ float sigm(float x) {
  return __builtin_amdgcn_rcpf(1.f + __builtin_amdgcn_exp2f(-1.4426950408889634f * x));
}
static __device__ __forceinline__ float tanh_(float x) {
  return 1.f - 2.f * __builtin_amdgcn_rcpf(1.f + __builtin_amdgcn_exp2f(2.8853900817779268f * x));
}

// device-coherent (bypass L1/L2) primitives
static __device__ __forceinline__ u32 poll_sc(const u32* p) {
  u32 v;
  asm volatile("global_load_dword %0, %1, off sc0 sc1\n\t"
               "s_waitcnt vmcnt(0)"
               : "=v"(v) : "v"(p) : "memory");
  return v;
}
static __device__ __forceinline__ void st16_sc(void* p, u32 v) {
  asm volatile("global_store_short %0, %1, off sc0 sc1" :: "v"(p), "v"(v) : "memory");
}
// issue 8 cached x loads (no wait)
static __device__ __forceinline__ void xissue(u32x4 x[8], const void* base) {
  asm volatile(
    "global_load_dwordx4 %0, %8, off offset:0\n\t"
    "global_load_dwordx4 %1, %8, off offset:64\n\t"
    "global_load_dwordx4 %2, %8, off offset:128\n\t"
    "global_load_dwordx4 %3, %8, off offset:192\n\t"
    "global_load_dwordx4 %4, %8, off offset:256\n\t"
    "global_load_dwordx4 %5, %8, off offset:320\n\t"
    "global_load_dwordx4 %6, %8, off offset:384\n\t"
    "global_load_dwordx4 %7, %8, off offset:448"
    : "=&v"(x[0]), "=&v"(x[1]), "=&v"(x[2]), "=&v"(x[3]),
      "=&v"(x[4]), "=&v"(x[5]), "=&v"(x[6]), "=&v"(x[7])
    : "v"(base) : "memory");
}
// issue 16 device-coherent staging loads (no wait); wave-local rows, stride 1KB
static __device__ __forceinline__ void sissue(u32x4 s[16], const char* b) {
  asm volatile(
    "global_load_dwordx4 %0, %16, off sc0 sc1\n\t"
    "global_load_dwordx4 %1, %17, off sc0 sc1\n\t"
    "global_load_dwordx4 %2, %18, off sc0 sc1\n\t"
    "global_load_dwordx4 %3, %19, off sc0 sc1\n\t"
    "global_load_dwordx4 %4, %20, off sc0 sc1\n\t"
    "global_load_dwordx4 %5, %21, off sc0 sc1\n\t"
    "global_load_dwordx4 %6, %22, off sc0 sc1\n\t"
    "global_load_dwordx4 %7, %23, off sc0 sc1\n\t"
    "global_load_dwordx4 %8, %24, off sc0 sc1\n\t"
    "global_load_dwordx4 %9, %25, off sc0 sc1\n\t"
    "global_load_dwordx4 %10, %26, off sc0 sc1\n\t"
    "global_load_dwordx4 %11, %27, off sc0 sc1\n\t"
    "global_load_dwordx4 %12, %28, off sc0 sc1\n\t"
    "global_load_dwordx4 %13, %29, off sc0 sc1\n\t"
    "global_load_dwordx4 %14, %30, off sc0 sc1\n\t"
    "global_load_dwordx4 %15, %31, off sc0 sc1"
    : "=&v"(s[0]), "=&v"(s[1]), "=&v"(s[2]), "=&v"(s[3]),
      "=&v"(s[4]), "=&v"(s[5]), "=&v"(s[6]), "=&v"(s[7]),
      "=&v"(s[8]), "=&v"(s[9]), "=&v"(s[10]), "=&v"(s[11]),
      "=&v"(s[12]), "=&v"(s[13]), "=&v"(s[14]), "=&v"(s[15])
    : "v"(b), "v"(b + 1024), "v"(b + 2048), "v"(b + 3072),
      "v"(b + 4096), "v"(b + 5120), "v"(b + 6144), "v"(b + 7168),
      "v"(b + 8192), "v"(b + 9216), "v"(b + 10240), "v"(b + 11264),
      "v"(b + 12288), "v"(b + 13312), "v"(b + 14336), "v"(b + 15360)
    : "memory");
}
static __device__ __forceinline__ void wait16() {
  asm volatile("s_waitcnt vmcnt(16)" ::: "memory");
  __builtin_amdgcn_sched_barrier(0);
}
static __device__ __forceinline__ void wait0() {
  asm volatile("s_waitcnt vmcnt(0)" ::: "memory");
  __builtin_amdgcn_sched_barrier(0);
}

__global__ void cvt_x(const float* __restrict__ x, u16* __restrict__ xb) {
  int i = blockIdx.x * 256 + threadIdx.x;          // one float4 per thread
  float4 v = ((const float4*)x)[i];
  ushort4 o;
  o.x = f2bf(v.x); o.y = f2bf(v.y); o.z = f2bf(v.z); o.w = f2bf(v.w);
  ((ushort4*)xb)[i] = o;
}

// 256 WGs: group = wg&7 owns batch rows [grp*64,+64); wgN = wg>>3 owns hidden
// cols [wgN*16,+16) of all 4 gates. Wave wv owns rows wv*16..+16 end-to-end:
// independent sync plane (per-[grp][wv] counter), zero __syncthreads in loop.
// W_hh fragments live permanently in registers (256 VGPR/lane).
__global__ void __launch_bounds__(256, 1) lstm_main(
    const u16* __restrict__ xb,
    const float* __restrict__ W_ih, const float* __restrict__ W_hh,
    const float* __restrict__ b_ih, const float* __restrict__ b_hh,
    const float* __restrict__ W_out, const float* __restrict__ b_out,
    float* __restrict__ out, char* __restrict__ ws)
{
  __shared__ char smem[LDS_TOTAL];
  const int tid = threadIdx.x;
  const int wg  = blockIdx.x;
  const int grp = wg & 7;
  const int wgN = wg >> 3;
  const int lane = tid & 63;
  const int wv   = tid >> 6;
  const int cc = lane & 15;
  const int hi = lane >> 4;
  const int c7 = cc & 7;

  // ---- one-time: weight slice -> LDS, bf16, XOR-swizzled (row = gate*16+lc) ----
  for (int i = tid; i < 64 * 192; i += 256) {
    int r = i / 192;
    int k = (i - r * 192) * 4;
    int n = (r >> 4) * 512 + wgN * 16 + (r & 15);
    float4 v = (k < 256) ? *(const float4*)(W_ih + n * 256 + k)
                         : *(const float4*)(W_hh + n * 512 + (k - 256));
    u32 lo  = (u32)f2bf(v.x) | ((u32)f2bf(v.y) << 16);
    u32 hi2 = (u32)f2bf(v.z) | ((u32)f2bf(v.w) << 16);
    int addr = r * W_ROWB + ((k * 2) ^ ((r & 7) << 4));
    *(uint2*)(smem + addr) = make_uint2(lo, hi2);
  }

  float bv[4];
  #pragma unroll
  for (int nt = 0; nt < 4; ++nt) {
    int n = nt * 512 + wgN * 16 + cc;
    bv[nt] = b_ih[n] + b_hh[n];
  }

  u32* cntp = (u32*)(ws + CNT_OFF + grp * 512 + wv * 128);
  char* slices = ws + SL_OFF;
  const char* grpsl = slices + (size_t)grp * GRP_BYTES;

  const char* wrow[4];
  #pragma unroll
  for (int nt = 0; nt < 4; ++nt) wrow[nt] = smem + (nt * 16 + cc) * W_ROWB;
  const int hw = (hi * 16) ^ (c7 << 4);     // weight-image fragment swizzle

  const u16* xrow = xb + (size_t)(grp * 64 + wv * 16 + cc) * 65536 + hi * 8;
  const int abase = H_OFF + (wv * 16 + cc) * 1024;   // A-frag row base (own plane)

  __syncthreads();

  // ---- W_hh fragments -> registers, once (16 kc x 4 gates x 4 VGPR) ----
  bf16x8 bh[16][4];
  #pragma unroll
  for (int kc = 0; kc < 16; ++kc)
    #pragma unroll
    for (int nt = 0; nt < 4; ++nt)
      bh[kc][nt] = *(const bf16x8*)(wrow[nt] + (((kc + 8) * 64) ^ hw));

  float cst[4] = {0.f, 0.f, 0.f, 0.f};      // fp32 cell state

  #pragma unroll 1
  for (int t = 0; t < NSTEPS; ++t) {
    u32x4 xreg[8];
    xissue(xreg, xrow + (size_t)t * 256);

    if (t > 0) {
      u32 tgt = 32u * (u32)t;
      while (poll_sc(cntp) < tgt) __builtin_amdgcn_s_sleep(1);
    }

    // ---- stage own 16 h-rows (read slot = (t&1)^1), overlap with x-part ----
    const char* rdslot = grpsl + (size_t)((t & 1) ^ 1) * SLOT_BYTES
                       + wv * 16384 + lane * 16;
    u32x4 sv[16];
    sissue(sv, rdslot);
    wait16();                               // x loads (oldest 8) complete

    f32x4 acc[4] = {};
    #pragma unroll
    for (int kc = 0; kc < 8; ++kc) {
      bf16x8 a = __builtin_bit_cast(bf16x8, xreg[kc]);
      #pragma unroll
      for (int nt = 0; nt < 4; ++nt) {
        bf16x8 b = *(const bf16x8*)(wrow[nt] + ((kc * 64) ^ hw));
        acc[nt] = __builtin_amdgcn_mfma_f32_16x16x32_bf16(a, b, acc[nt], 0, 0, 0);
      }
    }

    wait0();                                // staging loads complete
    #pragma unroll
    for (int it = 0; it < 16; ++it) {       // wave-local rows: no barrier needed
      int row = wv * 16 + it;
      *(u32x4*)(smem + H_OFF + row * 1024 + ((lane ^ (row & 7)) << 4)) = sv[it];
    }

    // ---- h-part: A from own LDS rows, B from registers ----
    #pragma unroll
    for (int kc = 0; kc < 16; ++kc) {
      bf16x8 a = *(const bf16x8*)(smem + abase + (((kc * 4 + hi) ^ c7) << 4));
      #pragma unroll
      for (int nt = 0; nt < 4; ++nt)
        acc[nt] = __builtin_amdgcn_mfma_f32_16x16x32_bf16(a, bh[kc][nt], acc[nt], 0, 0, 0);
    }

    // ---- gates (nt = gate, lane-local), state update, h store (plain layout) ----
    char* wdst = slices + (size_t)(t & 1) * SLOT_BYTES + grp * GRP_BYTES;
    const int colb = (wgN * 16 + cc) * 2;
    #pragma unroll
    for (int r = 0; r < 4; ++r) {
      float gi = acc[0][r] + bv[0];
      float gf = acc[1][r] + bv[1];
      float gg = acc[2][r] + bv[2];
      float go = acc[3][r] + bv[3];
      float ii = sigm(gi), ff = sigm(gf), g2 = tanh_(gg), oo = sigm(go);
      float cn = ff * cst[r] + ii * g2;
      cst[r] = cn;
      float hn = oo * tanh_(cn);
      int row = wv * 16 + hi * 4 + r;
      st16_sc(wdst + row * 1024 + colb, (u32)f2bf(hn));
    }
    asm volatile("s_waitcnt vmcnt(0)" ::: "memory");   // own stores at coherence point
    if (lane == 0) atomicAdd(cntp, 1u);                // per-wave plane signal
  }

  // ---- head: one WG per group computes out = h_T @ W_out^T + b_out ----
  if (wgN == 0) {
    while (poll_sc(cntp) < 32u * NSTEPS) __builtin_amdgcn_s_sleep(1);
    const char* src = grpsl + SLOT_BYTES + wv * 16384 + lane * 16;  // slot 1 = h_255
    u32x4 sv[16];
    sissue(sv, src);
    wait0();
    #pragma unroll
    for (int it = 0; it < 16; ++it) {
      int row = wv * 16 + it;
      *(u32x4*)(smem + H_OFF + row * 1024 + ((lane ^ (row & 7)) << 4)) = sv[it];
    }
    __syncthreads();                         // cross-wave read below
    int b = tid >> 2, q = tid & 3;
    float s = 0.f;
    for (int j = q * 128; j < q * 128 + 128; ++j) {
      int g = (j >> 3) ^ (b & 7);
      s += bf2f(*(const u16*)(smem + H_OFF + b * 1024 + g * 16 + (j & 7) * 2)) * W_out[j];
    }
    s += __shfl_xor(s, 1);
    s += __shfl_xor(s, 2);
    if (q == 0) out[grp * 64 + b] = s + b_out[0];
  }
}

extern "C" void kernel_launch(void* const* d_in, const int* in_sizes, int n_in,
                              void* d_out, int out_size, void* d_ws, size_t ws_size,
                              hipStream_t stream) {
  (void)in_sizes; (void)n_in; (void)out_size; (void)ws_size;
  const float* x     = (const float*)d_in[0];
  const float* W_ih  = (const float*)d_in[1];
  const float* W_hh  = (const float*)d_in[2];
  const float* b_ih  = (const float*)d_in[3];
  const float* b_hh  = (const float*)d_in[4];
  const float* W_out = (const float*)d_in[5];
  const float* b_out = (const float*)d_in[6];
  char* ws = (char*)d_ws;

  // zero h-exchange slots + per-plane counters (re-runs every graph replay)
  hipMemsetAsync(ws + SL_OFF, 0, 2u * SLOT_BYTES + 4096u, stream);
  cvt_x<<<32768, 256, 0, stream>>>(x, (u16*)ws);
  lstm_main<<<256, 256, 0, stream>>>((const u16*)ws, W_ih, W_hh, b_ih, b_hh,
                                     W_out, b_out, (float*)d_out, ws);
}

// Round 4
// 1224.264 us; speedup vs baseline: 1.7441x; 1.7441x over previous
//
#include <hip/hip_runtime.h>
#include <stdint.h>

typedef unsigned int u32;
typedef unsigned short u16;
typedef __attribute__((ext_vector_type(8))) __bf16 bf16x8;
typedef __attribute__((ext_vector_type(4))) float f32x4;
typedef __attribute__((ext_vector_type(4))) u32 u32x4;
typedef __attribute__((ext_vector_type(2))) u32 u32x2;

#define NSTEPS 256
// ---- workspace layout ----
#define XB_BYTES   67108864u              // x as bf16: 512*256*256*2
#define SL_OFF     XB_BYTES               // h slots: [slot][group][wgN][64 rows][16 cols] bf16
#define GRP_BYTES   65536u                // 32 wgN * 2KB
#define SLOT_BYTES  524288u               // 8 groups
#define CNT_OFF    (SL_OFF + 2u * SLOT_BYTES)
// ---- LDS layout ----
#define W_ROWB 1536                       // 768 bf16 per weight row (row = gate*16 + localcol)
#define H_OFF  98304                      // 64 rows * 1536
#define LDS_TOTAL 163840                  // + 64 rows * 1024 (h tile) = 160 KiB exactly

static __device__ __forceinline__ u16 f2bf(float f) {
  u32 u = __builtin_bit_cast(u32, f);
  return (u16)((u + 0x7fffu + ((u >> 16) & 1u)) >> 16);   // RNE
}
static __device__ __forceinline__ float bf2f(u16 h) {
  u32 u = ((u32)h) << 16;
  return __builtin_bit_cast(float, u);
}
static __device__ __forceinline__ float sigm(float x) {
  return __builtin_amdgcn_rcpf(1.f + __builtin_amdgcn_exp2f(-1.4426950408889634f * x));
}
static __device__ __forceinline__ float tanh_(float x) {
  return 1.f - 2.f * __builtin_amdgcn_rcpf(1.f + __builtin_amdgcn_exp2f(2.8853900817779268f * x));
}

// device-coherent (bypass L1/L2) primitives
static __device__ __forceinline__ u32 poll_sc(const u32* p) {
  u32 v;
  asm volatile("global_load_dword %0, %1, off sc0 sc1\n\t"
               "s_waitcnt vmcnt(0)"
               : "=v"(v) : "v"(p) : "memory");
  return v;
}
static __device__ __forceinline__ void st8_sc(void* p, u32x2 v) {
  asm volatile("global_store_dwordx2 %0, %1, off sc0 sc1" :: "v"(p), "v"(v) : "memory");
}
// issue 8 cached x loads (no wait)
static __device__ __forceinline__ void xissue(u32x4 x[8], const void* base) {
  asm volatile(
    "global_load_dwordx4 %0, %8, off offset:0\n\t"
    "global_load_dwordx4 %1, %8, off offset:64\n\t"
    "global_load_dwordx4 %2, %8, off offset:128\n\t"
    "global_load_dwordx4 %3, %8, off offset:192\n\t"
    "global_load_dwordx4 %4, %8, off offset:256\n\t"
    "global_load_dwordx4 %5, %8, off offset:320\n\t"
    "global_load_dwordx4 %6, %8, off offset:384\n\t"
    "global_load_dwordx4 %7, %8, off offset:448"
    : "=&v"(x[0]), "=&v"(x[1]), "=&v"(x[2]), "=&v"(x[3]),
      "=&v"(x[4]), "=&v"(x[5]), "=&v"(x[6]), "=&v"(x[7])
    : "v"(base) : "memory");
}
// issue 8 device-coherent staging loads (no wait); granule it at b + it*4096
static __device__ __forceinline__ void sissue8(u32x4 s[8], const char* b) {
  asm volatile(
    "global_load_dwordx4 %0, %8, off sc0 sc1\n\t"
    "global_load_dwordx4 %1, %9, off sc0 sc1\n\t"
    "global_load_dwordx4 %2, %10, off sc0 sc1\n\t"
    "global_load_dwordx4 %3, %11, off sc0 sc1\n\t"
    "global_load_dwordx4 %4, %12, off sc0 sc1\n\t"
    "global_load_dwordx4 %5, %13, off sc0 sc1\n\t"
    "global_load_dwordx4 %6, %14, off sc0 sc1\n\t"
    "global_load_dwordx4 %7, %15, off sc0 sc1"
    : "=&v"(s[0]), "=&v"(s[1]), "=&v"(s[2]), "=&v"(s[3]),
      "=&v"(s[4]), "=&v"(s[5]), "=&v"(s[6]), "=&v"(s[7])
    : "v"(b), "v"(b + 4096), "v"(b + 8192), "v"(b + 12288),
      "v"(b + 16384), "v"(b + 20480), "v"(b + 24576), "v"(b + 28672)
    : "memory");
}
static __device__ __forceinline__ void wait8() {
  asm volatile("s_waitcnt vmcnt(8)" ::: "memory");
  __builtin_amdgcn_sched_barrier(0);
}
static __device__ __forceinline__ void wait0() {
  asm volatile("s_waitcnt vmcnt(0)" ::: "memory");
  __builtin_amdgcn_sched_barrier(0);
}

__global__ void cvt_x(const float* __restrict__ x, u16* __restrict__ xb) {
  int i = blockIdx.x * 256 + threadIdx.x;          // one float4 per thread
  float4 v = ((const float4*)x)[i];
  ushort4 o;
  o.x = f2bf(v.x); o.y = f2bf(v.y); o.z = f2bf(v.z); o.w = f2bf(v.w);
  ((ushort4*)xb)[i] = o;
}

// 256 WGs: group = wg&7 owns batch rows [grp*64,+64); wgN = wg>>3 owns hidden
// cols [wgN*16,+16) of all 4 gates. MFMA operands SWAPPED (D = W·X^T):
// lane holds batch=lane&15, 4 consecutive hidden cols (hi*4+r) -> h-store is
// one coalesced dwordx2 per lane.
__global__ void __launch_bounds__(256, 1) lstm_main(
    const u16* __restrict__ xb,
    const float* __restrict__ W_ih, const float* __restrict__ W_hh,
    const float* __restrict__ b_ih, const float* __restrict__ b_hh,
    const float* __restrict__ W_out, const float* __restrict__ b_out,
    float* __restrict__ out, char* __restrict__ ws)
{
  __shared__ char smem[LDS_TOTAL];
  const int tid = threadIdx.x;
  const int wg  = blockIdx.x;
  const int grp = wg & 7;
  const int wgN = wg >> 3;
  const int lane = tid & 63;
  const int wv   = tid >> 6;
  const int cc = lane & 15;
  const int hi = lane >> 4;
  const int c7 = cc & 7;

  // ---- one-time: weight slice -> LDS, bf16, XOR-swizzled (row = gate*16+lc) ----
  for (int i = tid; i < 64 * 192; i += 256) {
    int r = i / 192;
    int k = (i - r * 192) * 4;
    int n = (r >> 4) * 512 + wgN * 16 + (r & 15);
    float4 v = (k < 256) ? *(const float4*)(W_ih + n * 256 + k)
                         : *(const float4*)(W_hh + n * 512 + (k - 256));
    u32 lo  = (u32)f2bf(v.x) | ((u32)f2bf(v.y) << 16);
    u32 hi2 = (u32)f2bf(v.z) | ((u32)f2bf(v.w) << 16);
    int addr = r * W_ROWB + ((k * 2) ^ ((r & 7) << 4));
    *(uint2*)(smem + addr) = make_uint2(lo, hi2);
  }

  // bias for this lane's 16 (gate, col) outputs: col = wgN*16 + hi*4 + r
  float bvn[4][4];
  #pragma unroll
  for (int nt = 0; nt < 4; ++nt)
    #pragma unroll
    for (int r = 0; r < 4; ++r) {
      int n = nt * 512 + wgN * 16 + hi * 4 + r;
      bvn[nt][r] = b_ih[n] + b_hh[n];
    }

  u32* cnt = (u32*)(ws + CNT_OFF + grp * 128);
  char* slices = ws + SL_OFF;
  const char* grpsl = slices + (size_t)grp * GRP_BYTES;

  const char* wrow[4];
  #pragma unroll
  for (int nt = 0; nt < 4; ++nt) wrow[nt] = smem + (nt * 16 + cc) * W_ROWB;
  const int hw = (hi * 16) ^ (c7 << 4);     // fragment granule swizzle

  const u16* xrow = xb + (size_t)(grp * 64 + wv * 16 + cc) * 65536 + hi * 8;
  const char* arow = smem + H_OFF + (wv * 16 + cc) * 1024;  // staged-h frag row

  // staging ds-write mapping (whole-WG cooperative, constant across t)
  const int srow  = (tid & 127) >> 1;       // = (tid>>1)&63
  const int shalf = tid & 1;
  const int swgb  = tid >> 7;
  char* sdst0 = smem + H_OFF + srow * 1024;
  const int sswz = (srow & 7) << 4;

  float cst[4] = {0.f, 0.f, 0.f, 0.f};      // fp32 cell state (batch cc, col hi*4+r)

  __syncthreads();

  #pragma unroll 1
  for (int t = 0; t < NSTEPS; ++t) {
    // ---- x-part: no h-dependency, runs before/while h_{t-1} is produced ----
    u32x4 xreg[8];
    xissue(xreg, xrow + (size_t)t * 256);
    wait0();

    f32x4 acc[4] = {};
    #pragma unroll
    for (int kc = 0; kc < 8; ++kc) {
      bf16x8 b = __builtin_bit_cast(bf16x8, xreg[kc]);
      #pragma unroll
      for (int nt = 0; nt < 4; ++nt) {
        bf16x8 a = *(const bf16x8*)(wrow[nt] + ((kc * 64) ^ hw));
        acc[nt] = __builtin_amdgcn_mfma_f32_16x16x32_bf16(a, b, acc[nt], 0, 0, 0);
      }
    }

    if (t > 0) {
      u32 tgt = 32u * (u32)t;
      while (poll_sc(cnt) < tgt) __builtin_amdgcn_s_sleep(1);
    }

    // ---- stage h_{t-1} (read slot = (t&1)^1), split 8+8 to overlap L3 RTT ----
    const char* rdslot = grpsl + (size_t)((t & 1) ^ 1) * SLOT_BYTES + tid * 16;
    u32x4 sv[16];
    sissue8(sv, rdslot);
    sissue8(sv + 8, rdslot + 32768);
    wait8();                                // first 8 granules (k 0..255 region)
    #pragma unroll
    for (int it = 0; it < 8; ++it) {
      int wgn = it * 2 + swgb;
      *(u32x4*)(sdst0 + ((wgn * 32 + shalf * 16) ^ sswz)) = sv[it];
    }
    __syncthreads();

    // ---- h-part kc 0..7 (k 256..511 of weights, k 0..255 of h) ----
    #pragma unroll
    for (int kc = 0; kc < 8; ++kc) {
      bf16x8 b = *(const bf16x8*)(arow + ((kc * 64) ^ hw));
      #pragma unroll
      for (int nt = 0; nt < 4; ++nt) {
        bf16x8 a = *(const bf16x8*)(wrow[nt] + (((kc + 8) * 64) ^ hw));
        acc[nt] = __builtin_amdgcn_mfma_f32_16x16x32_bf16(a, b, acc[nt], 0, 0, 0);
      }
    }

    wait0();                                // second 8 granules
    #pragma unroll
    for (int it = 8; it < 16; ++it) {
      int wgn = it * 2 + swgb;
      *(u32x4*)(sdst0 + ((wgn * 32 + shalf * 16) ^ sswz)) = sv[it];
    }
    __syncthreads();

    // ---- h-part kc 8..15 ----
    #pragma unroll
    for (int kc = 8; kc < 16; ++kc) {
      bf16x8 b = *(const bf16x8*)(arow + ((kc * 64) ^ hw));
      #pragma unroll
      for (int nt = 0; nt < 4; ++nt) {
        bf16x8 a = *(const bf16x8*)(wrow[nt] + (((kc + 8) * 64) ^ hw));
        acc[nt] = __builtin_amdgcn_mfma_f32_16x16x32_bf16(a, b, acc[nt], 0, 0, 0);
      }
    }

    // ---- gates (lane: batch cc, cols hi*4+0..3), pack, ONE dwordx2 store ----
    char* wdst = slices + (size_t)(t & 1) * SLOT_BYTES + grp * GRP_BYTES + wgN * 2048;
    u32x2 pk;
    u32 plo = 0, phi2 = 0;
    #pragma unroll
    for (int r = 0; r < 4; ++r) {
      float gi = acc[0][r] + bvn[0][r];
      float gf = acc[1][r] + bvn[1][r];
      float gg = acc[2][r] + bvn[2][r];
      float go = acc[3][r] + bvn[3][r];
      float ii = sigm(gi), ff = sigm(gf), g2 = tanh_(gg), oo = sigm(go);
      float cn = ff * cst[r] + ii * g2;
      cst[r] = cn;
      float hn = oo * tanh_(cn);
      u32 hb = (u32)f2bf(hn);
      if (r < 2) plo |= hb << (16 * r);
      else       phi2 |= hb << (16 * (r - 2));
    }
    pk[0] = plo; pk[1] = phi2;
    st8_sc(wdst + (wv * 16 + cc) * 32 + hi * 8, pk);

    wait0();                                // own store at coherence point
    __syncthreads();
    if (tid == 0) atomicAdd(cnt, 1u);
  }

  // ---- head: one WG per group computes out = h_T @ W_out^T + b_out ----
  if (wgN == 0) {
    while (poll_sc(cnt) < 32u * NSTEPS) __builtin_amdgcn_s_sleep(1);
    const char* src = grpsl + SLOT_BYTES + tid * 16;   // slot 1 = h_255
    u32x4 sv[16];
    sissue8(sv, src);
    sissue8(sv + 8, src + 32768);
    wait0();
    #pragma unroll
    for (int it = 0; it < 16; ++it) {
      int wgn = it * 2 + swgb;
      *(u32x4*)(smem + H_OFF + srow * 1024 + wgn * 32 + shalf * 16) = sv[it];  // linear
    }
    __syncthreads();
    int b = tid >> 2, q = tid & 3;
    float s = 0.f;
    for (int j = q * 128; j < q * 128 + 128; ++j)
      s += bf2f(*(const u16*)(smem + H_OFF + b * 1024 + j * 2)) * W_out[j];
    s += __shfl_xor(s, 1);
    s += __shfl_xor(s, 2);
    if (q == 0) out[grp * 64 + b] = s + b_out[0];
  }
}

extern "C" void kernel_launch(void* const* d_in, const int* in_sizes, int n_in,
                              void* d_out, int out_size, void* d_ws, size_t ws_size,
                              hipStream_t stream) {
  (void)in_sizes; (void)n_in; (void)out_size; (void)ws_size;
  const float* x     = (const float*)d_in[0];
  const float* W_ih  = (const float*)d_in[1];
  const float* W_hh  = (const float*)d_in[2];
  const float* b_ih  = (const float*)d_in[3];
  const float* b_hh  = (const float*)d_in[4];
  const float* W_out = (const float*)d_in[5];
  const float* b_out = (const float*)d_in[6];
  char* ws = (char*)d_ws;

  // zero h-exchange slots + group counters (re-runs every graph replay)
  hipMemsetAsync(ws + SL_OFF, 0, 2u * SLOT_BYTES + 1024u, stream);
  cvt_x<<<32768, 256, 0, stream>>>(x, (u16*)ws);
  lstm_main<<<256, 256, 0, stream>>>((const u16*)ws, W_ih, W_hh, b_ih, b_hh,
                                     W_out, b_out, (float*)d_out, ws);
}

// Round 5
// 1122.386 us; speedup vs baseline: 1.9024x; 1.0908x over previous
//
#include <hip/hip_runtime.h>
#include <stdint.h>

typedef unsigned int u32;
typedef unsigned short u16;
typedef __attribute__((ext_vector_type(8))) __bf16 bf16x8;
typedef __attribute__((ext_vector_type(4))) float f32x4;
typedef __attribute__((ext_vector_type(4))) u32 u32x4;
typedef __attribute__((ext_vector_type(2))) u32 u32x2;

#define NSTEPS 256
// ---- workspace layout ----
#define XB_BYTES   67108864u              // x as bf16: 512*256*256*2
#define SL_OFF     XB_BYTES               // h slots: [slot][group][wgN][row 0..63][c16 0..15] bf16
#define GRP_BYTES   65536u                // 32 wgN * 2048B
#define SLOT_BYTES  524288u               // 8 groups
#define CNT_OFF    (SL_OFF + 2u * SLOT_BYTES)
// ---- LDS: fragment-linear weights only ----
// granule(nt, kc, lane) at ((nt*24 + kc)*64 + lane)*16 ; 4*24*64*16 = 98304 B
#define LDS_TOTAL 98304

static __device__ __forceinline__ u16 f2bf(float f) {
  u32 u = __builtin_bit_cast(u32, f);
  return (u16)((u + 0x7fffu + ((u >> 16) & 1u)) >> 16);   // RNE
}
static __device__ __forceinline__ float bf2f(u16 h) {
  u32 u = ((u32)h) << 16;
  return __builtin_bit_cast(float, u);
}
static __device__ __forceinline__ float sigm(float x) {
  return __builtin_amdgcn_rcpf(1.f + __builtin_amdgcn_exp2f(-1.4426950408889634f * x));
}
static __device__ __forceinline__ float tanh_(float x) {
  return 1.f - 2.f * __builtin_amdgcn_rcpf(1.f + __builtin_amdgcn_exp2f(2.8853900817779268f * x));
}

// device-coherent (bypass L1/L2) primitives
static __device__ __forceinline__ u32 poll_sc(const u32* p) {
  u32 v;
  asm volatile("global_load_dword %0, %1, off sc0 sc1\n\t"
               "s_waitcnt vmcnt(0)"
               : "=v"(v) : "v"(p) : "memory");
  return v;
}
static __device__ __forceinline__ void st8_sc(void* p, u32x2 v) {
  asm volatile("global_store_dwordx2 %0, %1, off sc0 sc1" :: "v"(p), "v"(v) : "memory");
}
static __device__ __forceinline__ u32x4 ld16_sc_wait(const void* p) {
  u32x4 v;
  asm volatile("global_load_dwordx4 %0, %1, off sc0 sc1\n\t"
               "s_waitcnt vmcnt(0)"
               : "=v"(v) : "v"(p) : "memory");
  return v;
}
// issue 8 cached x loads (no wait)
static __device__ __forceinline__ void xissue(u32x4 x[8], const void* base) {
  asm volatile(
    "global_load_dwordx4 %0, %8, off offset:0\n\t"
    "global_load_dwordx4 %1, %8, off offset:64\n\t"
    "global_load_dwordx4 %2, %8, off offset:128\n\t"
    "global_load_dwordx4 %3, %8, off offset:192\n\t"
    "global_load_dwordx4 %4, %8, off offset:256\n\t"
    "global_load_dwordx4 %5, %8, off offset:320\n\t"
    "global_load_dwordx4 %6, %8, off offset:384\n\t"
    "global_load_dwordx4 %7, %8, off offset:448"
    : "=&v"(x[0]), "=&v"(x[1]), "=&v"(x[2]), "=&v"(x[3]),
      "=&v"(x[4]), "=&v"(x[5]), "=&v"(x[6]), "=&v"(x[7])
    : "v"(base) : "memory");
}
// issue 16 device-coherent A-fragment loads (no wait); stride 4096 B (kc)
static __device__ __forceinline__ void aissue(u32x4 s[16], const char* b) {
  asm volatile(
    "global_load_dwordx4 %0, %16, off sc0 sc1\n\t"
    "global_load_dwordx4 %1, %17, off sc0 sc1\n\t"
    "global_load_dwordx4 %2, %18, off sc0 sc1\n\t"
    "global_load_dwordx4 %3, %19, off sc0 sc1\n\t"
    "global_load_dwordx4 %4, %20, off sc0 sc1\n\t"
    "global_load_dwordx4 %5, %21, off sc0 sc1\n\t"
    "global_load_dwordx4 %6, %22, off sc0 sc1\n\t"
    "global_load_dwordx4 %7, %23, off sc0 sc1\n\t"
    "global_load_dwordx4 %8, %24, off sc0 sc1\n\t"
    "global_load_dwordx4 %9, %25, off sc0 sc1\n\t"
    "global_load_dwordx4 %10, %26, off sc0 sc1\n\t"
    "global_load_dwordx4 %11, %27, off sc0 sc1\n\t"
    "global_load_dwordx4 %12, %28, off sc0 sc1\n\t"
    "global_load_dwordx4 %13, %29, off sc0 sc1\n\t"
    "global_load_dwordx4 %14, %30, off sc0 sc1\n\t"
    "global_load_dwordx4 %15, %31, off sc0 sc1"
    : "=&v"(s[0]), "=&v"(s[1]), "=&v"(s[2]), "=&v"(s[3]),
      "=&v"(s[4]), "=&v"(s[5]), "=&v"(s[6]), "=&v"(s[7]),
      "=&v"(s[8]), "=&v"(s[9]), "=&v"(s[10]), "=&v"(s[11]),
      "=&v"(s[12]), "=&v"(s[13]), "=&v"(s[14]), "=&v"(s[15])
    : "v"(b), "v"(b + 4096), "v"(b + 8192), "v"(b + 12288),
      "v"(b + 16384), "v"(b + 20480), "v"(b + 24576), "v"(b + 28672),
      "v"(b + 32768), "v"(b + 36864), "v"(b + 40960), "v"(b + 45056),
      "v"(b + 49152), "v"(b + 53248), "v"(b + 57344), "v"(b + 61440)
    : "memory");
}
#define AWAIT(N) do { asm volatile("s_waitcnt vmcnt(" #N ")" ::: "memory"); \
                      __builtin_amdgcn_sched_barrier(0); } while (0)

__global__ void cvt_x(const float* __restrict__ x, u16* __restrict__ xb) {
  int i = blockIdx.x * 256 + threadIdx.x;          // one float4 per thread
  float4 v = ((const float4*)x)[i];
  ushort4 o;
  o.x = f2bf(v.x); o.y = f2bf(v.y); o.z = f2bf(v.z); o.w = f2bf(v.w);
  ((ushort4*)xb)[i] = o;
}

// 256 WGs: group = wg&7 owns batch rows [grp*64,+64); wgN = wg>>3 owns hidden
// cols [wgN*16,+16) of all 4 gates. Swapped MFMA (D = W·X^T): lane holds
// batch=lane&15, hidden cols hi*4+r. h-part weights pinned in 256 VGPRs;
// h fragments loaded DIRECTLY from the global slot (no LDS staging).
__global__ void __launch_bounds__(256, 1) lstm_main(
    const u16* __restrict__ xb,
    const float* __restrict__ W_ih, const float* __restrict__ W_hh,
    const float* __restrict__ b_ih, const float* __restrict__ b_hh,
    const float* __restrict__ W_out, const float* __restrict__ b_out,
    float* __restrict__ out, char* __restrict__ ws)
{
  __shared__ char smem[LDS_TOTAL];
  const int tid = threadIdx.x;
  const int wg  = blockIdx.x;
  const int grp = wg & 7;
  const int wgN = wg >> 3;
  const int lane = tid & 63;
  const int wv   = tid >> 6;
  const int cc = lane & 15;
  const int hi = lane >> 4;

  // ---- one-time: weight slice -> LDS, fragment-linear (conflict-free) ----
  {
    const int lane_in = tid & 63;
    const int lc = lane_in & 15, hh = lane_in >> 4;
    #pragma unroll
    for (int nt = 0; nt < 4; ++nt)
      #pragma unroll
      for (int it = 0; it < 6; ++it) {
        int kcc = (tid >> 6) + it * 4;          // 0..23
        int n = nt * 512 + wgN * 16 + lc;
        int k = kcc * 32 + hh * 8;
        float4 v0, v1;
        if (kcc < 8) {
          v0 = *(const float4*)(W_ih + n * 256 + k);
          v1 = *(const float4*)(W_ih + n * 256 + k + 4);
        } else {
          int k2 = k - 256;
          v0 = *(const float4*)(W_hh + n * 512 + k2);
          v1 = *(const float4*)(W_hh + n * 512 + k2 + 4);
        }
        u32x4 g;
        g[0] = (u32)f2bf(v0.x) | ((u32)f2bf(v0.y) << 16);
        g[1] = (u32)f2bf(v0.z) | ((u32)f2bf(v0.w) << 16);
        g[2] = (u32)f2bf(v1.x) | ((u32)f2bf(v1.y) << 16);
        g[3] = (u32)f2bf(v1.z) | ((u32)f2bf(v1.w) << 16);
        *(u32x4*)(smem + ((nt * 24 + kcc) * 64 + lane_in) * 16) = g;
      }
  }

  // bias for this lane's 16 (gate, col) outputs: col = wgN*16 + hi*4 + r
  float bvn[4][4];
  #pragma unroll
  for (int nt = 0; nt < 4; ++nt)
    #pragma unroll
    for (int r = 0; r < 4; ++r) {
      int n = nt * 512 + wgN * 16 + hi * 4 + r;
      bvn[nt][r] = b_ih[n] + b_hh[n];
    }

  u32* cnt = (u32*)(ws + CNT_OFF + grp * 128);
  char* slices = ws + SL_OFF;
  const char* grpsl = slices + (size_t)grp * GRP_BYTES;

  const u16* xrow = xb + (size_t)(grp * 64 + wv * 16 + cc) * 65536 + hi * 8;
  // A-fragment per-lane base inside slot (stride 4096 per kc)
  const int afrag = (hi >> 1) * 2048 + (wv * 16 + cc) * 32 + (hi & 1) * 16;

  __syncthreads();

  // ---- pin h-part weight fragments in 256 VGPRs (kc 8..23 of full row) ----
  bf16x8 bh[16][4];
  #pragma unroll
  for (int kc = 0; kc < 16; ++kc)
    #pragma unroll
    for (int nt = 0; nt < 4; ++nt)
      bh[kc][nt] = *(const bf16x8*)(smem + ((nt * 24 + kc + 8) * 64 + lane) * 16);
  #pragma unroll
  for (int kc = 0; kc < 16; ++kc)
    #pragma unroll
    for (int nt = 0; nt < 4; ++nt)
      asm volatile("" : "+v"(bh[kc][nt]));      // opaque: forbid remat, force regs

  float cst[4] = {0.f, 0.f, 0.f, 0.f};          // fp32 cell state

  u32x4 xreg[8];
  xissue(xreg, xrow);                            // prefetch x_0

  #pragma unroll 1
  for (int t = 0; t < NSTEPS; ++t) {
    if (t > 0) {
      u32 tgt = 32u * (u32)t;
      while (poll_sc(cnt) < tgt) __builtin_amdgcn_s_sleep(1);
    }

    // ---- issue 16 direct h-fragment loads (L3 RTT hides under x-part) ----
    const char* rds = grpsl + (size_t)((t & 1) ^ 1) * SLOT_BYTES;
    u32x4 av[16];
    aissue(av, rds + afrag);

    AWAIT(16);                                   // x_t complete (A still in flight)
    f32x4 acc[4] = {};
    #pragma unroll
    for (int kc = 0; kc < 8; ++kc) {
      bf16x8 b = __builtin_bit_cast(bf16x8, xreg[kc]);
      #pragma unroll
      for (int nt = 0; nt < 4; ++nt) {
        bf16x8 a = *(const bf16x8*)(smem + ((nt * 24 + kc) * 64 + lane) * 16);
        acc[nt] = __builtin_amdgcn_mfma_f32_16x16x32_bf16(a, b, acc[nt], 0, 0, 0);
      }
    }

    // ---- h-part from pinned weights, counted-vmcnt chunks ----
    AWAIT(12);
    #pragma unroll
    for (int kc = 0; kc < 4; ++kc) {
      bf16x8 b = __builtin_bit_cast(bf16x8, av[kc]);
      #pragma unroll
      for (int nt = 0; nt < 4; ++nt)
        acc[nt] = __builtin_amdgcn_mfma_f32_16x16x32_bf16(bh[kc][nt], b, acc[nt], 0, 0, 0);
    }
    AWAIT(8);
    #pragma unroll
    for (int kc = 4; kc < 8; ++kc) {
      bf16x8 b = __builtin_bit_cast(bf16x8, av[kc]);
      #pragma unroll
      for (int nt = 0; nt < 4; ++nt)
        acc[nt] = __builtin_amdgcn_mfma_f32_16x16x32_bf16(bh[kc][nt], b, acc[nt], 0, 0, 0);
    }
    AWAIT(4);
    #pragma unroll
    for (int kc = 8; kc < 12; ++kc) {
      bf16x8 b = __builtin_bit_cast(bf16x8, av[kc]);
      #pragma unroll
      for (int nt = 0; nt < 4; ++nt)
        acc[nt] = __builtin_amdgcn_mfma_f32_16x16x32_bf16(bh[kc][nt], b, acc[nt], 0, 0, 0);
    }
    AWAIT(0);
    #pragma unroll
    for (int kc = 12; kc < 16; ++kc) {
      bf16x8 b = __builtin_bit_cast(bf16x8, av[kc]);
      #pragma unroll
      for (int nt = 0; nt < 4; ++nt)
        acc[nt] = __builtin_amdgcn_mfma_f32_16x16x32_bf16(bh[kc][nt], b, acc[nt], 0, 0, 0);
    }

    // ---- gates (lane: batch cc, cols hi*4+0..3), pack, ONE dwordx2 store ----
    char* wdst = slices + (size_t)(t & 1) * SLOT_BYTES + grp * GRP_BYTES + wgN * 2048;
    u32 plo = 0, phi2 = 0;
    #pragma unroll
    for (int r = 0; r < 4; ++r) {
      float gi = acc[0][r] + bvn[0][r];
      float gf = acc[1][r] + bvn[1][r];
      float gg = acc[2][r] + bvn[2][r];
      float go = acc[3][r] + bvn[3][r];
      float ii = sigm(gi), ff = sigm(gf), g2 = tanh_(gg), oo = sigm(go);
      float cn = ff * cst[r] + ii * g2;
      cst[r] = cn;
      float hn = oo * tanh_(cn);
      u32 hb = (u32)f2bf(hn);
      if (r < 2) plo |= hb << (16 * r);
      else       phi2 |= hb << (16 * (r - 2));
    }
    u32x2 pk; pk[0] = plo; pk[1] = phi2;
    st8_sc(wdst + (wv * 16 + cc) * 32 + hi * 8, pk);

    AWAIT(0);                                    // own store at coherence point
    __syncthreads();
    if (tid == 0) atomicAdd(cnt, 1u);
    if (t + 1 < NSTEPS)
      xissue(xreg, xrow + (size_t)(t + 1) * 256);   // prefetch next x
  }

  // ---- head: one WG per group computes out = h_T @ W_out^T + b_out ----
  if (wgN == 0) {
    while (poll_sc(cnt) < 32u * NSTEPS) __builtin_amdgcn_s_sleep(1);
    const char* src = grpsl + SLOT_BYTES;        // slot 1 = h_255
    int b = tid >> 2, q = tid & 3;
    float s = 0.f;
    #pragma unroll
    for (int j16 = 0; j16 < 8; ++j16) {
      int nblk = q * 8 + j16;                    // wgN' block
      const char* p = src + nblk * 2048 + b * 32;
      u32x4 w0 = ld16_sc_wait(p);
      u32x4 w1 = ld16_sc_wait(p + 16);
      #pragma unroll
      for (int d = 0; d < 4; ++d) {
        int jb = q * 128 + j16 * 16 + d * 2;
        s += bf2f((u16)(w0[d] & 0xffff)) * W_out[jb];
        s += bf2f((u16)(w0[d] >> 16))    * W_out[jb + 1];
        s += bf2f((u16)(w1[d] & 0xffff)) * W_out[jb + 8];
        s += bf2f((u16)(w1[d] >> 16))    * W_out[jb + 9];
      }
    }
    s += __shfl_xor(s, 1);
    s += __shfl_xor(s, 2);
    if (q == 0) out[grp * 64 + b] = s + b_out[0];
  }
}

extern "C" void kernel_launch(void* const* d_in, const int* in_sizes, int n_in,
                              void* d_out, int out_size, void* d_ws, size_t ws_size,
                              hipStream_t stream) {
  (void)in_sizes; (void)n_in; (void)out_size; (void)ws_size;
  const float* x     = (const float*)d_in[0];
  const float* W_ih  = (const float*)d_in[1];
  const float* W_hh  = (const float*)d_in[2];
  const float* b_ih  = (const float*)d_in[3];
  const float* b_hh  = (const float*)d_in[4];
  const float* W_out = (const float*)d_in[5];
  const float* b_out = (const float*)d_in[6];
  char* ws = (char*)d_ws;

  // zero h-exchange slots + group counters (re-runs every graph replay)
  hipMemsetAsync(ws + SL_OFF, 0, 2u * SLOT_BYTES + 1024u, stream);
  cvt_x<<<32768, 256, 0, stream>>>(x, (u16*)ws);
  lstm_main<<<256, 256, 0, stream>>>((const u16*)ws, W_ih, W_hh, b_ih, b_hh,
                                     W_out, b_out, (float*)d_out, ws);
}